// Round 12
// baseline (319.391 us; speedup 1.0000x reference)
//
#include <hip/hip_runtime.h>
#include <hip/hip_bf16.h>
#include <hip/hip_cooperative_groups.h>

namespace cg = cooperative_groups;

#define C 128            // C_IN == C_OUT == 128
#define TPB 256
#define BWID 512         // nodes per coarse bucket (bucket = node >> 9)
#define NBUK 256         // buckets / partition blocks: supports N <= 131072

typedef __attribute__((ext_vector_type(8))) _Float16 half8;
typedef __attribute__((ext_vector_type(4))) float f32x4;
typedef __attribute__((ext_vector_type(2))) float fv2;
typedef unsigned long long u64;

// ---------------- workspace layout (bytes) ----------------
#define OFF_BSS   0x400      // int[257] bucket edge-starts (src partition)
#define OFF_BSD   0xC00      // int[257] bucket edge-starts (dst partition)
#define OFF_CSUM  0x1400     // int[512] column totals (S then D)
#define OFF_HISTS 0x10000    // int[256*256] per-(block,bucket) src counts -> local prefix
#define OFF_HISTD 0x50000    // int[256*256] same for dst
#define OFF_OFFS  0xA0000    // int[N]   CSR row offsets
#define OFF_CNTS  0x110000   // int[N]   out-degree
#define OFF_INVD  0x180000   // float[N] 1/(in-degree+1)
#define OFF_EDST  0x200000   // int[E]   CSR adjacency
#define OFF_HN    0x900000   // bf16[N*128] hn = (x@W^T) * invd
// d_out staging (dead until gather rewrites out): src32[E], dst32[E],
// partS u64[E], partD int[E]. 7E ints = 44.8 MB <= out 51.2 MB.

__device__ __forceinline__ unsigned f2bf_bits(float f) {
    unsigned u = __float_as_uint(f);
    return (u + 0x7fffu + ((u >> 16) & 1u)) >> 16;   // RNE
}

// ONE cooperative kernel for the whole CSR build: detect -> hist+stage ->
// colscan -> bscan -> scatter -> csr+deg. 256 blocks x 256 thr, all phases
// low-VGPR, ~13KB LDS -> co-resident. Replaces 7 serial launches.
__global__ __launch_bounds__(TPB) void build_kernel(
        const void* __restrict__ edges, long long E, int chunk,
        int* __restrict__ src32, int* __restrict__ dst32,
        int* __restrict__ histS, int* __restrict__ histD,
        int* __restrict__ csum, int* __restrict__ bsS, int* __restrict__ bsD,
        u64* __restrict__ partS, int* __restrict__ partD,
        int* __restrict__ offS, int* __restrict__ cntS,
        int* __restrict__ eDst, float* __restrict__ invd, int N) {
    cg::grid_group grid = cg::this_grid();
    const int t = threadIdx.x;
    const int B = blockIdx.x;
    const long long b0 = (long long)B * chunk;

    __shared__ int flag_s;
    __shared__ int hs[NBUK], hd[NBUK];
    __shared__ int sc[TPB];
    __shared__ int cs2[NBUK], cd2[NBUK];
    __shared__ int cnt[BWID], off[BWID];
    __shared__ int dcnt[BWID];

    // ---- P-1: per-block dtype detect (uniform outcome, no global flag) ----
    if (t == 0) flag_s = 0;
    __syncthreads();
    {
        const unsigned* ew = (const unsigned*)edges;
        int any = 0;
        for (int k = t; k < 1024; k += TPB) {
            const long long widx = 2LL * k + 1;        // odd word: int64 hi or src32[2k+1]
            if (widx < 2 * E) any |= (ew[widx] != 0u);
        }
        if (any) atomicOr(&flag_s, 1);                 // LDS
    }
    __syncthreads();
    const int is32 = flag_s;

    // ---- P0: decode + stage src32/dst32 + LDS bucket histograms ----
    hs[t] = 0; hd[t] = 0;
    __syncthreads();
    for (int i = t; i < chunk; i += TPB) {
        const long long e = b0 + i;
        if (e < E) {
            int s, d;
            if (is32) {
                const int* p = (const int*)edges;
                s = p[e]; d = p[E + e];
            } else {
                const long long* p = (const long long*)edges;
                s = (int)p[e]; d = (int)p[E + e];
            }
            src32[e] = s;
            dst32[e] = d;
            atomicAdd(&hs[s >> 9], 1);                 // LDS atomic
            atomicAdd(&hd[d >> 9], 1);
        }
    }
    __syncthreads();
    histS[B * NBUK + t] = hs[t];
    histD[B * NBUK + t] = hd[t];
    grid.sync();

    // ---- P1: column scan (block B scans column B of histS, then histD) ----
    {
        int v = histS[t * NBUK + B];
        sc[t] = v;
        __syncthreads();
        for (int d = 1; d < TPB; d <<= 1) {
            const int a = (t >= d) ? sc[t - d] : 0;
            __syncthreads();
            sc[t] += a;
            __syncthreads();
        }
        histS[t * NBUK + B] = sc[t] - v;               // exclusive within column
        if (t == TPB - 1) csum[B] = sc[t];
        __syncthreads();
        v = histD[t * NBUK + B];
        sc[t] = v;
        __syncthreads();
        for (int d = 1; d < TPB; d <<= 1) {
            const int a = (t >= d) ? sc[t - d] : 0;
            __syncthreads();
            sc[t] += a;
            __syncthreads();
        }
        histD[t * NBUK + B] = sc[t] - v;
        if (t == TPB - 1) csum[NBUK + B] = sc[t];
    }
    grid.sync();

    // ---- P2: scan of column totals -> bucket starts (blocks 0 and 1) ----
    if (B < 2) {
        int* bs = B ? bsD : bsS;
        const int v = csum[B * NBUK + t];
        sc[t] = v;
        __syncthreads();
        for (int d = 1; d < TPB; d <<= 1) {
            const int a = (t >= d) ? sc[t - d] : 0;
            __syncthreads();
            sc[t] += a;
            __syncthreads();
        }
        bs[t] = sc[t] - v;
        if (t == TPB - 1) bs[NBUK] = (int)E;
    }
    grid.sync();

    // ---- P3: scatter into coarse buckets (contiguous per-(block,bucket)
    // runs via LDS cursors; zero global atomics) ----
    cs2[t] = histS[B * NBUK + t] + bsS[t];
    cd2[t] = histD[B * NBUK + t] + bsD[t];
    __syncthreads();
    for (int i = t; i < chunk; i += TPB) {
        const long long e = b0 + i;
        if (e < E) {
            const int sv = src32[e], dv = dst32[e];
            const int ps = atomicAdd(&cs2[sv >> 9], 1);  // LDS atomic
            partS[ps] = ((u64)(unsigned)dv << 32) | (unsigned)sv;
            const int pd = atomicAdd(&cd2[dv >> 9], 1);
            partD[pd] = dv;
        }
    }
    grid.sync();

    // ---- P4: per-bucket counting sort (CSR) + in-degree -> invd ----
    const int lo = B * BWID;
    if (lo < N) {
        const int eb = bsS[B], ee = bsS[B + 1];
        cnt[t] = 0; cnt[t + TPB] = 0;
        __syncthreads();
        for (int e = eb + t; e < ee; e += TPB)
            atomicAdd(&cnt[(int)(partS[e] & 0xffffffffu) - lo], 1);
        __syncthreads();
        const int c0 = cnt[2 * t], c1 = cnt[2 * t + 1];
        const int loc = c0 + c1;
        sc[t] = loc;
        __syncthreads();
        for (int d = 1; d < TPB; d <<= 1) {
            const int a = (t >= d) ? sc[t - d] : 0;
            __syncthreads();
            sc[t] += a;
            __syncthreads();
        }
        const int ex = sc[t] - loc;
        off[2 * t] = ex;
        off[2 * t + 1] = ex + c0;
        __syncthreads();
        for (int i = t; i < BWID; i += TPB) {
            const int node = lo + i;
            if (node < N) { offS[node] = eb + off[i]; cntS[node] = cnt[i]; }
        }
        __syncthreads();
        for (int e = eb + t; e < ee; e += TPB) {
            const u64 p = partS[e];
            const int sv = (int)(p & 0xffffffffu);
            const int dv = (int)(p >> 32);
            const int pos = atomicAdd(&off[sv - lo], 1); // LDS atomic
            eDst[eb + pos] = dv;
        }
        // in-degree from dst partition
        const int db = bsD[B], de = bsD[B + 1];
        dcnt[t] = 0; dcnt[t + TPB] = 0;
        __syncthreads();
        for (int e = db + t; e < de; e += TPB)
            atomicAdd(&dcnt[partD[e] - lo], 1);
        __syncthreads();
        for (int i = t; i < BWID; i += TPB) {
            const int node = lo + i;
            if (node < N) invd[node] = 1.0f / (float)(dcnt[i] + 1);
        }
    }
}

// hn[i][:] = bf16( (x[i] @ W^T) * invd[i] )  via mfma_f32_16x16x32_f16.
// W read as f32 and converted in-register (W is L2-resident).
__global__ __launch_bounds__(TPB) void gemm_mfma_kernel(const float* __restrict__ x,
                                                        const float* __restrict__ W,
                                                        const float* __restrict__ invd,
                                                        unsigned short* __restrict__ hn,
                                                        int N) {
    const int t = threadIdx.x;
    const int lane = t & 63;
    const int wid = t >> 6;
    const int lr = lane & 15;      // row (A) / col (B) within fragment
    const int lk = lane >> 4;      // k-block (0..3)
    const int m0 = blockIdx.x * 128 + wid * 32;

    half8 a[2][4];
#pragma unroll
    for (int mb = 0; mb < 2; ++mb) {
        const int row = m0 + mb * 16 + lr;
        const float* xp = x + (size_t)row * C + lk * 8;
#pragma unroll
        for (int ks = 0; ks < 4; ++ks) {
            half8 av;
            if (row < N) {
                const float4 v0 = *(const float4*)(xp + ks * 32);
                const float4 v1 = *(const float4*)(xp + ks * 32 + 4);
                av[0] = (_Float16)v0.x; av[1] = (_Float16)v0.y;
                av[2] = (_Float16)v0.z; av[3] = (_Float16)v0.w;
                av[4] = (_Float16)v1.x; av[5] = (_Float16)v1.y;
                av[6] = (_Float16)v1.z; av[7] = (_Float16)v1.w;
            } else {
                av = (half8)((_Float16)0.f);
            }
            a[mb][ks] = av;
        }
    }

    f32x4 acc[2][8];
#pragma unroll
    for (int mb = 0; mb < 2; ++mb)
#pragma unroll
        for (int nf = 0; nf < 8; ++nf)
            acc[mb][nf] = (f32x4){0.f, 0.f, 0.f, 0.f};

#pragma unroll
    for (int nf = 0; nf < 8; ++nf) {
        half8 b[4];
        const float* wp = W + (size_t)(nf * 16 + lr) * C + lk * 8;
#pragma unroll
        for (int ks = 0; ks < 4; ++ks) {
            const float4 w0 = *(const float4*)(wp + ks * 32);
            const float4 w1 = *(const float4*)(wp + ks * 32 + 4);
            half8 bv;
            bv[0] = (_Float16)w0.x; bv[1] = (_Float16)w0.y;
            bv[2] = (_Float16)w0.z; bv[3] = (_Float16)w0.w;
            bv[4] = (_Float16)w1.x; bv[5] = (_Float16)w1.y;
            bv[6] = (_Float16)w1.z; bv[7] = (_Float16)w1.w;
            b[ks] = bv;
        }
#pragma unroll
        for (int mb = 0; mb < 2; ++mb)
#pragma unroll
            for (int ks = 0; ks < 4; ++ks)
                acc[mb][nf] = __builtin_amdgcn_mfma_f32_16x16x32_f16(
                    a[mb][ks], b[ks], acc[mb][nf], 0, 0, 0);
    }

#pragma unroll
    for (int mb = 0; mb < 2; ++mb) {
#pragma unroll
        for (int r = 0; r < 4; ++r) {
            const int row = m0 + mb * 16 + lk * 4 + r;
            if (row < N) {
                const float idv = invd[row];
                unsigned short* hp = hn + (size_t)row * C + lr;
#pragma unroll
                for (int nf = 0; nf < 8; ++nf)
                    hp[nf * 16] = (unsigned short)f2bf_bits(acc[mb][nf][r] * idv);
            }
        }
    }
}

// One wave per node. Lane = (sub, ll): 16 lanes x uint4 = one 256B hn row,
// 4 sub-groups process 4 neighbors per memory instruction. Self-loop is a
// virtual (cnt+1)-th item. Cross-sub reduce via shfl_xor(16/32).
__global__ __launch_bounds__(TPB) void gather_kernel(const int* __restrict__ offS,
                                                     const int* __restrict__ cntS,
                                                     const int* __restrict__ eDst,
                                                     const uint4* __restrict__ hnb4,
                                                     const float* __restrict__ invd,
                                                     float* __restrict__ out, int N) {
    const int lane = threadIdx.x & 63;
    const int w = (blockIdx.x * TPB + threadIdx.x) >> 6;
    if (w >= N) return;
    const int sub = lane >> 4;     // 0..3: neighbor within group of 4
    const int ll  = lane & 15;     // 16B chunk within row
    const int beg = offS[w];
    const int cnt = cntS[w];
    const int total = cnt + 1;     // + self loop

    float acc[8];
#pragma unroll
    for (int i = 0; i < 8; ++i) acc[i] = 0.f;

    for (int j0 = 0; j0 < total; j0 += 64) {
        const int m = min(64, total - j0);
        int dl = w;                                      // virtual self item
        if (lane < m && j0 + lane < cnt)
            dl = __builtin_nontemporal_load(&eDst[beg + j0 + lane]);
#pragma unroll 4
        for (int q = 0; q < m; q += 4) {
            const int d = __shfl(dl, q + sub);
            if (q + sub < m) {
                const uint4 v = hnb4[(size_t)d * 16 + ll];
                acc[0] += __uint_as_float(v.x << 16);
                acc[1] += __uint_as_float(v.x & 0xffff0000u);
                acc[2] += __uint_as_float(v.y << 16);
                acc[3] += __uint_as_float(v.y & 0xffff0000u);
                acc[4] += __uint_as_float(v.z << 16);
                acc[5] += __uint_as_float(v.z & 0xffff0000u);
                acc[6] += __uint_as_float(v.w << 16);
                acc[7] += __uint_as_float(v.w & 0xffff0000u);
            }
        }
    }

#pragma unroll
    for (int i = 0; i < 8; ++i) {
        acc[i] += __shfl_xor(acc[i], 16);
        acc[i] += __shfl_xor(acc[i], 32);
    }

    const float s = invd[w];
    fv2 o;
    o.x = acc[sub * 2] * s;
    o.y = acc[sub * 2 + 1] * s;
    fv2* op = (fv2*)(out + (size_t)w * C + ll * 8 + sub * 2);
    __builtin_nontemporal_store(o, op);
}

extern "C" void kernel_launch(void* const* d_in, const int* in_sizes, int n_in,
                              void* d_out, int out_size, void* d_ws, size_t ws_size,
                              hipStream_t stream) {
    const float* x = (const float*)d_in[0];
    const void* edges = d_in[1];
    const float* W = (const float*)d_in[2];
    float* out = (float*)d_out;

    const int N = in_sizes[0] / C;
    const long long E = (long long)in_sizes[1] / 2;

    char* ws = (char*)d_ws;
    int*       bsS   = (int*)(ws + OFF_BSS);
    int*       bsD   = (int*)(ws + OFF_BSD);
    int*       csum  = (int*)(ws + OFF_CSUM);
    int*       histS = (int*)(ws + OFF_HISTS);
    int*       histD = (int*)(ws + OFF_HISTD);
    int*       offS  = (int*)(ws + OFF_OFFS);
    int*       cntS  = (int*)(ws + OFF_CNTS);
    float*     invd  = (float*)(ws + OFF_INVD);
    int*       eDst  = (int*)(ws + OFF_EDST);
    unsigned short* hn = (unsigned short*)(ws + OFF_HN);

    // staging in d_out (dead until gather rewrites every element)
    int* o32   = (int*)d_out;
    int* src32 = o32;
    int* dst32 = o32 + E;
    u64* partS = (u64*)(o32 + 2 * E);
    int* partD = o32 + 6 * E;

    int chunk = (int)((E + NBUK - 1) / NBUK);               // 6250
    int Ni = N;
    long long Ev = E;

    void* args[] = { (void*)&edges, (void*)&Ev, (void*)&chunk,
                     (void*)&src32, (void*)&dst32,
                     (void*)&histS, (void*)&histD, (void*)&csum,
                     (void*)&bsS, (void*)&bsD,
                     (void*)&partS, (void*)&partD,
                     (void*)&offS, (void*)&cntS, (void*)&eDst, (void*)&invd,
                     (void*)&Ni };
    hipLaunchCooperativeKernel((void*)build_kernel, dim3(NBUK), dim3(TPB),
                               args, 0, stream);

    const int nBlkG = (N + 127) / 128;                      // 782
    gemm_mfma_kernel<<<nBlkG, TPB, 0, stream>>>(x, W, invd, hn, N);

    const int nBlkA = (N * 64 + TPB - 1) / TPB;             // 25000 (wave per node)
    gather_kernel<<<nBlkA, TPB, 0, stream>>>(offS, cntS, eDst, (const uint4*)hn,
                                             invd, out, N);
}

// Round 13
// 171.592 us; speedup vs baseline: 1.8613x; 1.8613x over previous
//
#include <hip/hip_runtime.h>
#include <hip/hip_bf16.h>

#define C 128            // C_IN == C_OUT == 128
#define TPB 256
#define TPB2 512         // big blocks for latency-bound build kernels (8 waves/CU)
#define BWID 512         // nodes per coarse bucket (bucket = node >> 9)
#define NBUK 256         // buckets / partition blocks: supports N <= 131072

typedef __attribute__((ext_vector_type(8))) _Float16 half8;
typedef __attribute__((ext_vector_type(4))) float f32x4;
typedef __attribute__((ext_vector_type(2))) float fv2;
typedef unsigned long long u64;

// ---------------- workspace layout (bytes) ----------------
#define OFF_BSS   0x400      // int[257] bucket edge-starts (src partition)
#define OFF_BSD   0xC00      // int[257] bucket edge-starts (dst partition)
#define OFF_CSUM  0x1400     // int[512] column totals (S then D)
#define OFF_HISTS 0x10000    // int[256*256] per-(block,bucket) src counts -> local prefix
#define OFF_HISTD 0x50000    // int[256*256] same for dst
#define OFF_OFFS  0xA0000    // int[N]   CSR row offsets
#define OFF_CNTS  0x110000   // int[N]   out-degree
#define OFF_INVD  0x180000   // float[N] 1/(in-degree+1)
#define OFF_EDST  0x200000   // int[E]   CSR adjacency
#define OFF_HN    0x900000   // bf16[N*128] hn = (x@W^T) * invd
// d_out staging (dead until gather rewrites out): src32[E], dst32[E],
// partS u64[E], partD int[E]. 7E ints = 44.8 MB <= out 51.2 MB.

__device__ __forceinline__ unsigned f2bf_bits(float f) {
    unsigned u = __float_as_uint(f);
    return (u + 0x7fffu + ((u >> 16) & 1u)) >> 16;   // RNE
}

// Decode edges (int64/int32) -> src32/dst32 + per-block LDS bucket
// histograms. Dtype detect folded in (per-block, uniform outcome).
__global__ __launch_bounds__(TPB2) void hist_kernel(const void* __restrict__ edges,
                                                    long long E, int chunk,
                                                    int* __restrict__ src32,
                                                    int* __restrict__ dst32,
                                                    int* __restrict__ histS,
                                                    int* __restrict__ histD) {
    __shared__ int flag_s;
    __shared__ int hs[NBUK], hd[NBUK];
    const int t = threadIdx.x;
    const int B = blockIdx.x;
    if (t == 0) flag_s = 0;
    if (t < NBUK) { hs[t] = 0; hd[t] = 0; }
    __syncthreads();
    {   // detect: odd 32-bit words of the first 2048 edge entries
        const unsigned* ew = (const unsigned*)edges;
        int any = 0;
        for (int k = t; k < 2048; k += TPB2) {
            const long long widx = 2LL * k + 1;
            if (widx < 2 * E) any |= (ew[widx] != 0u);
        }
        if (any) atomicOr(&flag_s, 1);               // LDS
    }
    __syncthreads();
    const int is32 = flag_s;
    const long long b0 = (long long)B * chunk;
    for (int i = t; i < chunk; i += TPB2) {
        const long long e = b0 + i;
        if (e < E) {
            int s, d;
            if (is32) {
                const int* p = (const int*)edges;
                s = p[e]; d = p[E + e];
            } else {
                const long long* p = (const long long*)edges;
                s = (int)p[e]; d = (int)p[E + e];
            }
            src32[e] = s;
            dst32[e] = d;
            atomicAdd(&hs[s >> 9], 1);               // LDS atomic
            atomicAdd(&hd[d >> 9], 1);
        }
    }
    __syncthreads();
    if (t < NBUK) {
        histS[B * NBUK + t] = hs[t];
        histD[B * NBUK + t] = hd[t];
    }
}

// Parallel per-bucket column scan: block b (of 2*NBUK) scans column b of
// histS (b<NBUK) or histD over 256 partition rows. -> exclusive prefix;
// column total -> csum.
__global__ __launch_bounds__(TPB) void colscan_kernel(int* __restrict__ histS,
                                                      int* __restrict__ histD,
                                                      int* __restrict__ csum) {
    __shared__ int s[TPB];
    const int t = threadIdx.x;
    const int which = blockIdx.x >> 8;
    const int b = blockIdx.x & (NBUK - 1);
    int* hist = which ? histD : histS;
    const int v = hist[t * NBUK + b];
    s[t] = v;
    __syncthreads();
    for (int d = 1; d < TPB; d <<= 1) {
        const int a = (t >= d) ? s[t - d] : 0;
        __syncthreads();
        s[t] += a;
        __syncthreads();
    }
    hist[t * NBUK + b] = s[t] - v;                   // exclusive within column
    if (t == TPB - 1) csum[which * NBUK + b] = s[t]; // column total
}

// One block: exclusive scan of the 256 column totals -> bucket starts.
__global__ __launch_bounds__(TPB) void bscan_kernel(const int* __restrict__ csum,
                                                    int* __restrict__ bsS,
                                                    int* __restrict__ bsD, int Etot) {
    __shared__ int s[TPB];
    const int t = threadIdx.x;
    int v = csum[t];
    s[t] = v;
    __syncthreads();
    for (int d = 1; d < TPB; d <<= 1) {
        const int a = (t >= d) ? s[t - d] : 0;
        __syncthreads();
        s[t] += a;
        __syncthreads();
    }
    bsS[t] = s[t] - v;
    if (t == TPB - 1) bsS[NBUK] = Etot;
    __syncthreads();
    v = csum[NBUK + t];
    s[t] = v;
    __syncthreads();
    for (int d = 1; d < TPB; d <<= 1) {
        const int a = (t >= d) ? s[t - d] : 0;
        __syncthreads();
        s[t] += a;
        __syncthreads();
    }
    bsD[t] = s[t] - v;
    if (t == TPB - 1) bsD[NBUK] = Etot;
}

// Partition edges into coarse buckets. LDS cursors = local prefix + bucket
// start -> contiguous per-(block,bucket) runs, zero global atomics.
__global__ __launch_bounds__(TPB2) void scatter_kernel(const int* __restrict__ src32,
                                                       const int* __restrict__ dst32,
                                                       long long E, int chunk,
                                                       const int* __restrict__ histS,
                                                       const int* __restrict__ histD,
                                                       const int* __restrict__ bsS,
                                                       const int* __restrict__ bsD,
                                                       u64* __restrict__ partS,
                                                       int* __restrict__ partD) {
    __shared__ int cs[NBUK], cd[NBUK];
    const int t = threadIdx.x;
    const int B = blockIdx.x;
    if (t < NBUK) {
        cs[t] = histS[B * NBUK + t] + bsS[t];
        cd[t] = histD[B * NBUK + t] + bsD[t];
    }
    __syncthreads();
    const long long b0 = (long long)B * chunk;
    for (int i = t; i < chunk; i += TPB2) {
        const long long e = b0 + i;
        if (e < E) {
            const int sv = src32[e], dv = dst32[e];
            const int ps = atomicAdd(&cs[sv >> 9], 1);   // LDS atomic
            partS[ps] = ((u64)(unsigned)dv << 32) | (unsigned)sv;
            const int pd = atomicAdd(&cd[dv >> 9], 1);
            partD[pd] = dv;
        }
    }
}

// Per-bucket counting sort (CSR) + in-degree -> invd. One block per bucket.
__global__ __launch_bounds__(TPB2) void csrdeg_kernel(const u64* __restrict__ partS,
                                                      const int* __restrict__ partD,
                                                      const int* __restrict__ bsS,
                                                      const int* __restrict__ bsD,
                                                      int* __restrict__ offS,
                                                      int* __restrict__ cntS,
                                                      int* __restrict__ eDst,
                                                      float* __restrict__ invd, int N) {
    __shared__ int cnt[BWID], off[BWID], s[TPB2];
    const int t = threadIdx.x;
    const int B = blockIdx.x;
    const int lo = B * BWID;
    if (lo >= N) return;
    const int eb = bsS[B], ee = bsS[B + 1];
    cnt[t] = 0;                                      // TPB2 == BWID
    __syncthreads();
    for (int e = eb + t; e < ee; e += TPB2)
        atomicAdd(&cnt[(int)(partS[e] & 0xffffffffu) - lo], 1);
    __syncthreads();
    const int loc = cnt[t];
    s[t] = loc;
    __syncthreads();
    for (int d = 1; d < TPB2; d <<= 1) {
        const int a = (t >= d) ? s[t - d] : 0;
        __syncthreads();
        s[t] += a;
        __syncthreads();
    }
    const int ex = s[t] - loc;
    off[t] = ex;
    const int node = lo + t;
    if (node < N) { offS[node] = eb + ex; cntS[node] = loc; }
    __syncthreads();
    for (int e = eb + t; e < ee; e += TPB2) {
        const u64 p = partS[e];
        const int sv = (int)(p & 0xffffffffu);
        const int dv = (int)(p >> 32);
        const int pos = atomicAdd(&off[sv - lo], 1); // LDS atomic
        eDst[eb + pos] = dv;
    }
    // ---- in-degree from dst partition (reuse cnt) ----
    __syncthreads();
    cnt[t] = 0;
    __syncthreads();
    const int db = bsD[B], de = bsD[B + 1];
    for (int e = db + t; e < de; e += TPB2)
        atomicAdd(&cnt[partD[e] - lo], 1);
    __syncthreads();
    if (node < N) invd[node] = 1.0f / (float)(cnt[t] + 1);
}

// hn[i][:] = bf16( (x[i] @ W^T) * invd[i] )  via mfma_f32_16x16x32_f16.
// W read as f32 and converted in-register (W is L2-resident).
__global__ __launch_bounds__(TPB) void gemm_mfma_kernel(const float* __restrict__ x,
                                                        const float* __restrict__ W,
                                                        const float* __restrict__ invd,
                                                        unsigned short* __restrict__ hn,
                                                        int N) {
    const int t = threadIdx.x;
    const int lane = t & 63;
    const int wid = t >> 6;
    const int lr = lane & 15;      // row (A) / col (B) within fragment
    const int lk = lane >> 4;      // k-block (0..3)
    const int m0 = blockIdx.x * 128 + wid * 32;

    half8 a[2][4];
#pragma unroll
    for (int mb = 0; mb < 2; ++mb) {
        const int row = m0 + mb * 16 + lr;
        const float* xp = x + (size_t)row * C + lk * 8;
#pragma unroll
        for (int ks = 0; ks < 4; ++ks) {
            half8 av;
            if (row < N) {
                const float4 v0 = *(const float4*)(xp + ks * 32);
                const float4 v1 = *(const float4*)(xp + ks * 32 + 4);
                av[0] = (_Float16)v0.x; av[1] = (_Float16)v0.y;
                av[2] = (_Float16)v0.z; av[3] = (_Float16)v0.w;
                av[4] = (_Float16)v1.x; av[5] = (_Float16)v1.y;
                av[6] = (_Float16)v1.z; av[7] = (_Float16)v1.w;
            } else {
                av = (half8)((_Float16)0.f);
            }
            a[mb][ks] = av;
        }
    }

    f32x4 acc[2][8];
#pragma unroll
    for (int mb = 0; mb < 2; ++mb)
#pragma unroll
        for (int nf = 0; nf < 8; ++nf)
            acc[mb][nf] = (f32x4){0.f, 0.f, 0.f, 0.f};

#pragma unroll
    for (int nf = 0; nf < 8; ++nf) {
        half8 b[4];
        const float* wp = W + (size_t)(nf * 16 + lr) * C + lk * 8;
#pragma unroll
        for (int ks = 0; ks < 4; ++ks) {
            const float4 w0 = *(const float4*)(wp + ks * 32);
            const float4 w1 = *(const float4*)(wp + ks * 32 + 4);
            half8 bv;
            bv[0] = (_Float16)w0.x; bv[1] = (_Float16)w0.y;
            bv[2] = (_Float16)w0.z; bv[3] = (_Float16)w0.w;
            bv[4] = (_Float16)w1.x; bv[5] = (_Float16)w1.y;
            bv[6] = (_Float16)w1.z; bv[7] = (_Float16)w1.w;
            b[ks] = bv;
        }
#pragma unroll
        for (int mb = 0; mb < 2; ++mb)
#pragma unroll
            for (int ks = 0; ks < 4; ++ks)
                acc[mb][nf] = __builtin_amdgcn_mfma_f32_16x16x32_f16(
                    a[mb][ks], b[ks], acc[mb][nf], 0, 0, 0);
    }

#pragma unroll
    for (int mb = 0; mb < 2; ++mb) {
#pragma unroll
        for (int r = 0; r < 4; ++r) {
            const int row = m0 + mb * 16 + lk * 4 + r;
            if (row < N) {
                const float idv = invd[row];
                unsigned short* hp = hn + (size_t)row * C + lr;
#pragma unroll
                for (int nf = 0; nf < 8; ++nf)
                    hp[nf * 16] = (unsigned short)f2bf_bits(acc[mb][nf][r] * idv);
            }
        }
    }
}

// One wave per node. Lane = (sub, ll): 16 lanes x uint4 = one 256B hn row,
// 4 sub-groups process 4 neighbors per memory instruction. Self-loop is a
// virtual (cnt+1)-th item. Cross-sub reduce via shfl_xor(16/32).
__global__ __launch_bounds__(TPB) void gather_kernel(const int* __restrict__ offS,
                                                     const int* __restrict__ cntS,
                                                     const int* __restrict__ eDst,
                                                     const uint4* __restrict__ hnb4,
                                                     const float* __restrict__ invd,
                                                     float* __restrict__ out, int N) {
    const int lane = threadIdx.x & 63;
    const int w = (blockIdx.x * TPB + threadIdx.x) >> 6;
    if (w >= N) return;
    const int sub = lane >> 4;     // 0..3: neighbor within group of 4
    const int ll  = lane & 15;     // 16B chunk within row
    const int beg = offS[w];
    const int cnt = cntS[w];
    const int total = cnt + 1;     // + self loop

    float acc[8];
#pragma unroll
    for (int i = 0; i < 8; ++i) acc[i] = 0.f;

    for (int j0 = 0; j0 < total; j0 += 64) {
        const int m = min(64, total - j0);
        int dl = w;                                      // virtual self item
        if (lane < m && j0 + lane < cnt)
            dl = __builtin_nontemporal_load(&eDst[beg + j0 + lane]);
#pragma unroll 4
        for (int q = 0; q < m; q += 4) {
            const int d = __shfl(dl, q + sub);
            if (q + sub < m) {
                const uint4 v = hnb4[(size_t)d * 16 + ll];
                acc[0] += __uint_as_float(v.x << 16);
                acc[1] += __uint_as_float(v.x & 0xffff0000u);
                acc[2] += __uint_as_float(v.y << 16);
                acc[3] += __uint_as_float(v.y & 0xffff0000u);
                acc[4] += __uint_as_float(v.z << 16);
                acc[5] += __uint_as_float(v.z & 0xffff0000u);
                acc[6] += __uint_as_float(v.w << 16);
                acc[7] += __uint_as_float(v.w & 0xffff0000u);
            }
        }
    }

#pragma unroll
    for (int i = 0; i < 8; ++i) {
        acc[i] += __shfl_xor(acc[i], 16);
        acc[i] += __shfl_xor(acc[i], 32);
    }

    const float s = invd[w];
    fv2 o;
    o.x = acc[sub * 2] * s;
    o.y = acc[sub * 2 + 1] * s;
    fv2* op = (fv2*)(out + (size_t)w * C + ll * 8 + sub * 2);
    __builtin_nontemporal_store(o, op);
}

extern "C" void kernel_launch(void* const* d_in, const int* in_sizes, int n_in,
                              void* d_out, int out_size, void* d_ws, size_t ws_size,
                              hipStream_t stream) {
    const float* x = (const float*)d_in[0];
    const void* edges = d_in[1];
    const float* W = (const float*)d_in[2];
    float* out = (float*)d_out;

    const int N = in_sizes[0] / C;
    const long long E = (long long)in_sizes[1] / 2;

    char* ws = (char*)d_ws;
    int*       bsS   = (int*)(ws + OFF_BSS);
    int*       bsD   = (int*)(ws + OFF_BSD);
    int*       csum  = (int*)(ws + OFF_CSUM);
    int*       histS = (int*)(ws + OFF_HISTS);
    int*       histD = (int*)(ws + OFF_HISTD);
    int*       offS  = (int*)(ws + OFF_OFFS);
    int*       cntS  = (int*)(ws + OFF_CNTS);
    float*     invd  = (float*)(ws + OFF_INVD);
    int*       eDst  = (int*)(ws + OFF_EDST);
    unsigned short* hn = (unsigned short*)(ws + OFF_HN);

    // staging in d_out (dead until gather rewrites every element)
    int* o32   = (int*)d_out;
    int* src32 = o32;
    int* dst32 = o32 + E;
    u64* partS = (u64*)(o32 + 2 * E);
    int* partD = o32 + 6 * E;

    const int chunk = (int)((E + NBUK - 1) / NBUK);         // 6250

    hist_kernel<<<NBUK, TPB2, 0, stream>>>(edges, E, chunk, src32, dst32,
                                           histS, histD);
    colscan_kernel<<<2 * NBUK, TPB, 0, stream>>>(histS, histD, csum);
    bscan_kernel<<<1, TPB, 0, stream>>>(csum, bsS, bsD, (int)E);
    scatter_kernel<<<NBUK, TPB2, 0, stream>>>(src32, dst32, E, chunk, histS, histD,
                                              bsS, bsD, partS, partD);
    csrdeg_kernel<<<NBUK, TPB2, 0, stream>>>(partS, partD, bsS, bsD,
                                             offS, cntS, eDst, invd, N);

    const int nBlkG = (N + 127) / 128;                      // 782
    gemm_mfma_kernel<<<nBlkG, TPB, 0, stream>>>(x, W, invd, hn, N);

    const int nBlkA = (N * 64 + TPB - 1) / TPB;             // 25000 (wave per node)
    gather_kernel<<<nBlkA, TPB, 0, stream>>>(offS, cntS, eDst, (const uint4*)hn,
                                             invd, out, N);
}

// Round 14
// 166.061 us; speedup vs baseline: 1.9233x; 1.0333x over previous
//
#include <hip/hip_runtime.h>
#include <hip/hip_bf16.h>

#define C 128            // C_IN == C_OUT == 128
#define TPB 256
#define TPB3 1024        // huge blocks for latency-bound build kernels (16 waves/CU)
#define BWID 512         // nodes per coarse bucket (bucket = node >> 9)
#define NBUK 256         // buckets / partition blocks: supports N <= 131072

typedef __attribute__((ext_vector_type(8))) _Float16 half8;
typedef __attribute__((ext_vector_type(4))) float f32x4;
typedef __attribute__((ext_vector_type(2))) float fv2;
typedef unsigned long long u64;

// ---------------- workspace layout (bytes) ----------------
#define OFF_BSS   0x400      // int[257] bucket edge-starts (src partition)
#define OFF_BSD   0xC00      // int[257] bucket edge-starts (dst partition)
#define OFF_CSUM  0x1400     // int[512] column totals (S then D)
#define OFF_HISTS 0x10000    // int[256*256] per-(block,bucket) src counts -> local prefix
#define OFF_HISTD 0x50000    // int[256*256] same for dst
#define OFF_OFFS  0xA0000    // int[N]   CSR row offsets
#define OFF_CNTS  0x110000   // int[N]   out-degree
#define OFF_INVD  0x180000   // float[N] 1/(in-degree+1)
#define OFF_EDST  0x200000   // int[E]   CSR adjacency
#define OFF_HN    0x900000   // bf16[N*128] hn = (x@W^T) * invd
// d_out staging (dead until gather rewrites out): src32[E], dst32[E],
// partS u64[E], partD int[E]. 7E ints = 44.8 MB <= out 51.2 MB.

__device__ __forceinline__ unsigned f2bf_bits(float f) {
    unsigned u = __float_as_uint(f);
    return (u + 0x7fffu + ((u >> 16) & 1u)) >> 16;   // RNE
}

// Decode edges (int64/int32) -> src32/dst32 + per-block LDS bucket
// histograms. Dtype detect folded in (per-block, uniform outcome).
__global__ __launch_bounds__(TPB3) void hist_kernel(const void* __restrict__ edges,
                                                    long long E, int chunk,
                                                    int* __restrict__ src32,
                                                    int* __restrict__ dst32,
                                                    int* __restrict__ histS,
                                                    int* __restrict__ histD) {
    __shared__ int flag_s;
    __shared__ int hs[NBUK], hd[NBUK];
    const int t = threadIdx.x;
    const int B = blockIdx.x;
    if (t == 0) flag_s = 0;
    if (t < NBUK) { hs[t] = 0; hd[t] = 0; }
    __syncthreads();
    {   // detect: odd 32-bit words of the first 2048 edge entries
        const unsigned* ew = (const unsigned*)edges;
        int any = 0;
        for (int k = t; k < 2048; k += TPB3) {
            const long long widx = 2LL * k + 1;
            if (widx < 2 * E) any |= (ew[widx] != 0u);
        }
        if (any) atomicOr(&flag_s, 1);               // LDS
    }
    __syncthreads();
    const int is32 = flag_s;
    const long long b0 = (long long)B * chunk;
    for (int i = t; i < chunk; i += TPB3) {
        const long long e = b0 + i;
        if (e < E) {
            int s, d;
            if (is32) {
                const int* p = (const int*)edges;
                s = p[e]; d = p[E + e];
            } else {
                const long long* p = (const long long*)edges;
                s = (int)p[e]; d = (int)p[E + e];
            }
            src32[e] = s;
            dst32[e] = d;
            atomicAdd(&hs[s >> 9], 1);               // LDS atomic
            atomicAdd(&hd[d >> 9], 1);
        }
    }
    __syncthreads();
    if (t < NBUK) {
        histS[B * NBUK + t] = hs[t];
        histD[B * NBUK + t] = hd[t];
    }
}

// Parallel per-bucket column scan: block b (of 2*NBUK) scans column b of
// histS (b<NBUK) or histD over 256 partition rows. -> exclusive prefix;
// column total -> csum.
__global__ __launch_bounds__(TPB) void colscan_kernel(int* __restrict__ histS,
                                                      int* __restrict__ histD,
                                                      int* __restrict__ csum) {
    __shared__ int s[TPB];
    const int t = threadIdx.x;
    const int which = blockIdx.x >> 8;
    const int b = blockIdx.x & (NBUK - 1);
    int* hist = which ? histD : histS;
    const int v = hist[t * NBUK + b];
    s[t] = v;
    __syncthreads();
    for (int d = 1; d < TPB; d <<= 1) {
        const int a = (t >= d) ? s[t - d] : 0;
        __syncthreads();
        s[t] += a;
        __syncthreads();
    }
    hist[t * NBUK + b] = s[t] - v;                   // exclusive within column
    if (t == TPB - 1) csum[which * NBUK + b] = s[t]; // column total
}

// One block: exclusive scan of the 256 column totals -> bucket starts.
__global__ __launch_bounds__(TPB) void bscan_kernel(const int* __restrict__ csum,
                                                    int* __restrict__ bsS,
                                                    int* __restrict__ bsD, int Etot) {
    __shared__ int s[TPB];
    const int t = threadIdx.x;
    int v = csum[t];
    s[t] = v;
    __syncthreads();
    for (int d = 1; d < TPB; d <<= 1) {
        const int a = (t >= d) ? s[t - d] : 0;
        __syncthreads();
        s[t] += a;
        __syncthreads();
    }
    bsS[t] = s[t] - v;
    if (t == TPB - 1) bsS[NBUK] = Etot;
    __syncthreads();
    v = csum[NBUK + t];
    s[t] = v;
    __syncthreads();
    for (int d = 1; d < TPB; d <<= 1) {
        const int a = (t >= d) ? s[t - d] : 0;
        __syncthreads();
        s[t] += a;
        __syncthreads();
    }
    bsD[t] = s[t] - v;
    if (t == TPB - 1) bsD[NBUK] = Etot;
}

// Partition edges into coarse buckets. LDS cursors = local prefix + bucket
// start -> contiguous per-(block,bucket) runs, zero global atomics.
__global__ __launch_bounds__(TPB3) void scatter_kernel(const int* __restrict__ src32,
                                                       const int* __restrict__ dst32,
                                                       long long E, int chunk,
                                                       const int* __restrict__ histS,
                                                       const int* __restrict__ histD,
                                                       const int* __restrict__ bsS,
                                                       const int* __restrict__ bsD,
                                                       u64* __restrict__ partS,
                                                       int* __restrict__ partD) {
    __shared__ int cs[NBUK], cd[NBUK];
    const int t = threadIdx.x;
    const int B = blockIdx.x;
    if (t < NBUK) {
        cs[t] = histS[B * NBUK + t] + bsS[t];
        cd[t] = histD[B * NBUK + t] + bsD[t];
    }
    __syncthreads();
    const long long b0 = (long long)B * chunk;
    for (int i = t; i < chunk; i += TPB3) {
        const long long e = b0 + i;
        if (e < E) {
            const int sv = src32[e], dv = dst32[e];
            const int ps = atomicAdd(&cs[sv >> 9], 1);   // LDS atomic
            partS[ps] = ((u64)(unsigned)dv << 32) | (unsigned)sv;
            const int pd = atomicAdd(&cd[dv >> 9], 1);
            partD[pd] = dv;
        }
    }
}

// Per-bucket counting sort (CSR) + in-degree -> invd. One block per bucket,
// 1024 threads (16 waves/CU). All barriers block-uniform; node-indexed ops
// gated to t < BWID.
__global__ __launch_bounds__(TPB3) void csrdeg_kernel(const u64* __restrict__ partS,
                                                      const int* __restrict__ partD,
                                                      const int* __restrict__ bsS,
                                                      const int* __restrict__ bsD,
                                                      int* __restrict__ offS,
                                                      int* __restrict__ cntS,
                                                      int* __restrict__ eDst,
                                                      float* __restrict__ invd, int N) {
    __shared__ int cnt[BWID], off[BWID], s[TPB3];
    const int t = threadIdx.x;
    const int B = blockIdx.x;
    const int lo = B * BWID;
    if (lo >= N) return;
    const int eb = bsS[B], ee = bsS[B + 1];
    if (t < BWID) cnt[t] = 0;
    __syncthreads();
    for (int e = eb + t; e < ee; e += TPB3)
        atomicAdd(&cnt[(int)(partS[e] & 0xffffffffu) - lo], 1);
    __syncthreads();
    const int loc = (t < BWID) ? cnt[t] : 0;
    s[t] = loc;
    __syncthreads();
    for (int d = 1; d < TPB3; d <<= 1) {
        const int a = (t >= d) ? s[t - d] : 0;
        __syncthreads();
        s[t] += a;
        __syncthreads();
    }
    const int ex = s[t] - loc;
    if (t < BWID) {
        off[t] = ex;
        const int node = lo + t;
        if (node < N) { offS[node] = eb + ex; cntS[node] = loc; }
    }
    __syncthreads();
    for (int e = eb + t; e < ee; e += TPB3) {
        const u64 p = partS[e];
        const int sv = (int)(p & 0xffffffffu);
        const int dv = (int)(p >> 32);
        const int pos = atomicAdd(&off[sv - lo], 1); // LDS atomic
        eDst[eb + pos] = dv;
    }
    // ---- in-degree from dst partition (reuse cnt) ----
    __syncthreads();
    if (t < BWID) cnt[t] = 0;
    __syncthreads();
    const int db = bsD[B], de = bsD[B + 1];
    for (int e = db + t; e < de; e += TPB3)
        atomicAdd(&cnt[partD[e] - lo], 1);
    __syncthreads();
    if (t < BWID) {
        const int node = lo + t;
        if (node < N) invd[node] = 1.0f / (float)(cnt[t] + 1);
    }
}

// hn[i][:] = bf16( (x[i] @ W^T) * invd[i] )  via mfma_f32_16x16x32_f16.
// W read as f32 and converted in-register (W is L2-resident).
__global__ __launch_bounds__(TPB) void gemm_mfma_kernel(const float* __restrict__ x,
                                                        const float* __restrict__ W,
                                                        const float* __restrict__ invd,
                                                        unsigned short* __restrict__ hn,
                                                        int N) {
    const int t = threadIdx.x;
    const int lane = t & 63;
    const int wid = t >> 6;
    const int lr = lane & 15;      // row (A) / col (B) within fragment
    const int lk = lane >> 4;      // k-block (0..3)
    const int m0 = blockIdx.x * 128 + wid * 32;

    half8 a[2][4];
#pragma unroll
    for (int mb = 0; mb < 2; ++mb) {
        const int row = m0 + mb * 16 + lr;
        const float* xp = x + (size_t)row * C + lk * 8;
#pragma unroll
        for (int ks = 0; ks < 4; ++ks) {
            half8 av;
            if (row < N) {
                const float4 v0 = *(const float4*)(xp + ks * 32);
                const float4 v1 = *(const float4*)(xp + ks * 32 + 4);
                av[0] = (_Float16)v0.x; av[1] = (_Float16)v0.y;
                av[2] = (_Float16)v0.z; av[3] = (_Float16)v0.w;
                av[4] = (_Float16)v1.x; av[5] = (_Float16)v1.y;
                av[6] = (_Float16)v1.z; av[7] = (_Float16)v1.w;
            } else {
                av = (half8)((_Float16)0.f);
            }
            a[mb][ks] = av;
        }
    }

    f32x4 acc[2][8];
#pragma unroll
    for (int mb = 0; mb < 2; ++mb)
#pragma unroll
        for (int nf = 0; nf < 8; ++nf)
            acc[mb][nf] = (f32x4){0.f, 0.f, 0.f, 0.f};

#pragma unroll
    for (int nf = 0; nf < 8; ++nf) {
        half8 b[4];
        const float* wp = W + (size_t)(nf * 16 + lr) * C + lk * 8;
#pragma unroll
        for (int ks = 0; ks < 4; ++ks) {
            const float4 w0 = *(const float4*)(wp + ks * 32);
            const float4 w1 = *(const float4*)(wp + ks * 32 + 4);
            half8 bv;
            bv[0] = (_Float16)w0.x; bv[1] = (_Float16)w0.y;
            bv[2] = (_Float16)w0.z; bv[3] = (_Float16)w0.w;
            bv[4] = (_Float16)w1.x; bv[5] = (_Float16)w1.y;
            bv[6] = (_Float16)w1.z; bv[7] = (_Float16)w1.w;
            b[ks] = bv;
        }
#pragma unroll
        for (int mb = 0; mb < 2; ++mb)
#pragma unroll
            for (int ks = 0; ks < 4; ++ks)
                acc[mb][nf] = __builtin_amdgcn_mfma_f32_16x16x32_f16(
                    a[mb][ks], b[ks], acc[mb][nf], 0, 0, 0);
    }

#pragma unroll
    for (int mb = 0; mb < 2; ++mb) {
#pragma unroll
        for (int r = 0; r < 4; ++r) {
            const int row = m0 + mb * 16 + lk * 4 + r;
            if (row < N) {
                const float idv = invd[row];
                unsigned short* hp = hn + (size_t)row * C + lr;
#pragma unroll
                for (int nf = 0; nf < 8; ++nf)
                    hp[nf * 16] = (unsigned short)f2bf_bits(acc[mb][nf][r] * idv);
            }
        }
    }
}

// One wave per node. Lane = (sub, ll): 16 lanes x uint4 = one 256B hn row,
// 4 sub-groups process 4 neighbors per memory instruction. Self-loop is a
// virtual (cnt+1)-th item. Cross-sub reduce via shfl_xor(16/32).
__global__ __launch_bounds__(TPB) void gather_kernel(const int* __restrict__ offS,
                                                     const int* __restrict__ cntS,
                                                     const int* __restrict__ eDst,
                                                     const uint4* __restrict__ hnb4,
                                                     const float* __restrict__ invd,
                                                     float* __restrict__ out, int N) {
    const int lane = threadIdx.x & 63;
    const int w = (blockIdx.x * TPB + threadIdx.x) >> 6;
    if (w >= N) return;
    const int sub = lane >> 4;     // 0..3: neighbor within group of 4
    const int ll  = lane & 15;     // 16B chunk within row
    const int beg = offS[w];
    const int cnt = cntS[w];
    const int total = cnt + 1;     // + self loop

    float acc[8];
#pragma unroll
    for (int i = 0; i < 8; ++i) acc[i] = 0.f;

    for (int j0 = 0; j0 < total; j0 += 64) {
        const int m = min(64, total - j0);
        int dl = w;                                      // virtual self item
        if (lane < m && j0 + lane < cnt)
            dl = __builtin_nontemporal_load(&eDst[beg + j0 + lane]);
#pragma unroll 4
        for (int q = 0; q < m; q += 4) {
            const int d = __shfl(dl, q + sub);
            if (q + sub < m) {
                const uint4 v = hnb4[(size_t)d * 16 + ll];
                acc[0] += __uint_as_float(v.x << 16);
                acc[1] += __uint_as_float(v.x & 0xffff0000u);
                acc[2] += __uint_as_float(v.y << 16);
                acc[3] += __uint_as_float(v.y & 0xffff0000u);
                acc[4] += __uint_as_float(v.z << 16);
                acc[5] += __uint_as_float(v.z & 0xffff0000u);
                acc[6] += __uint_as_float(v.w << 16);
                acc[7] += __uint_as_float(v.w & 0xffff0000u);
            }
        }
    }

#pragma unroll
    for (int i = 0; i < 8; ++i) {
        acc[i] += __shfl_xor(acc[i], 16);
        acc[i] += __shfl_xor(acc[i], 32);
    }

    const float s = invd[w];
    fv2 o;
    o.x = acc[sub * 2] * s;
    o.y = acc[sub * 2 + 1] * s;
    fv2* op = (fv2*)(out + (size_t)w * C + ll * 8 + sub * 2);
    __builtin_nontemporal_store(o, op);
}

extern "C" void kernel_launch(void* const* d_in, const int* in_sizes, int n_in,
                              void* d_out, int out_size, void* d_ws, size_t ws_size,
                              hipStream_t stream) {
    const float* x = (const float*)d_in[0];
    const void* edges = d_in[1];
    const float* W = (const float*)d_in[2];
    float* out = (float*)d_out;

    const int N = in_sizes[0] / C;
    const long long E = (long long)in_sizes[1] / 2;

    char* ws = (char*)d_ws;
    int*       bsS   = (int*)(ws + OFF_BSS);
    int*       bsD   = (int*)(ws + OFF_BSD);
    int*       csum  = (int*)(ws + OFF_CSUM);
    int*       histS = (int*)(ws + OFF_HISTS);
    int*       histD = (int*)(ws + OFF_HISTD);
    int*       offS  = (int*)(ws + OFF_OFFS);
    int*       cntS  = (int*)(ws + OFF_CNTS);
    float*     invd  = (float*)(ws + OFF_INVD);
    int*       eDst  = (int*)(ws + OFF_EDST);
    unsigned short* hn = (unsigned short*)(ws + OFF_HN);

    // staging in d_out (dead until gather rewrites every element)
    int* o32   = (int*)d_out;
    int* src32 = o32;
    int* dst32 = o32 + E;
    u64* partS = (u64*)(o32 + 2 * E);
    int* partD = o32 + 6 * E;

    const int chunk = (int)((E + NBUK - 1) / NBUK);         // 6250

    hist_kernel<<<NBUK, TPB3, 0, stream>>>(edges, E, chunk, src32, dst32,
                                           histS, histD);
    colscan_kernel<<<2 * NBUK, TPB, 0, stream>>>(histS, histD, csum);
    bscan_kernel<<<1, TPB, 0, stream>>>(csum, bsS, bsD, (int)E);
    scatter_kernel<<<NBUK, TPB3, 0, stream>>>(src32, dst32, E, chunk, histS, histD,
                                              bsS, bsD, partS, partD);
    csrdeg_kernel<<<NBUK, TPB3, 0, stream>>>(partS, partD, bsS, bsD,
                                             offS, cntS, eDst, invd, N);

    const int nBlkG = (N + 127) / 128;                      // 782
    gemm_mfma_kernel<<<nBlkG, TPB, 0, stream>>>(x, W, invd, hn, N);

    const int nBlkA = (N * 64 + TPB - 1) / TPB;             // 25000 (wave per node)
    gather_kernel<<<nBlkA, TPB, 0, stream>>>(offS, cntS, eDst, (const uint4*)hn,
                                             invd, out, N);
}